// Round 1
// baseline (4062.386 us; speedup 1.0000x reference)
//
#include <hip/hip_runtime.h>
#include <cstdint>

#define BATCH   65536
#define IN_DIM  640
#define LAT_DIM 2560
#define KSEL    32

// ================= Kernel 0: transpose Wd [640][2560] -> WdT bf16 [2560][640] =================
__global__ __launch_bounds__(256) void transpose_wd(
    const float* __restrict__ Wd,
    unsigned short* __restrict__ WdT)
{
  __shared__ float tile[32][33];
  const int tx = threadIdx.x & 31;
  const int ty = threadIdx.x >> 5;          // 0..7
  const int l0 = (blockIdx.x % (LAT_DIM / 32)) * 32;  // 80 l-tiles
  const int i0 = (blockIdx.x / (LAT_DIM / 32)) * 32;  // 20 i-tiles

#pragma unroll
  for (int s = 0; s < 4; ++s) {
    int i = i0 + ty + 8 * s;
    tile[ty + 8 * s][tx] = Wd[(size_t)i * LAT_DIM + l0 + tx];
  }
  __syncthreads();
#pragma unroll
  for (int s = 0; s < 4; ++s) {
    int l = l0 + ty + 8 * s;
    float v = tile[tx][ty + 8 * s];
    unsigned int b = __float_as_uint(v);
    unsigned int r = (b + 0x7fffu + ((b >> 16) & 1u)) >> 16;  // RNE bf16
    WdT[(size_t)l * IN_DIM + i0 + tx] = (unsigned short)r;
  }
}

// ================= Kernel 1: encoder GEMM  lat = x @ We^T + be  (fp32) =================
#define BM  128
#define BN  128
#define BKK 16

__global__ __launch_bounds__(256) void encoder_gemm(
    const float* __restrict__ x,    // [B][640]
    const float* __restrict__ We,   // [2560][640]
    const float* __restrict__ be,   // [2560]
    float* __restrict__ lat)        // [B][2560]
{
  __shared__ float As[BKK][BM + 4];
  __shared__ float Bs[BKK][BN + 4];

  const int t  = threadIdx.x;
  const int nt = blockIdx.x % (LAT_DIM / BN);   // 20
  const int mt = blockIdx.x / (LAT_DIM / BN);   // 512
  const int m0 = mt * BM, n0 = nt * BN;
  const int tn = t & 15, tm = t >> 4;

  float acc[8][8];
#pragma unroll
  for (int i = 0; i < 8; ++i)
#pragma unroll
    for (int j = 0; j < 8; ++j) acc[i][j] = 0.f;

  for (int kt = 0; kt < IN_DIM; kt += BKK) {
#pragma unroll
    for (int r = 0; r < 2; ++r) {
      int s = t + 256 * r;                 // 512 float4 slots per tile
      int row = s >> 2, kq = s & 3;
      float4 a4 = *(const float4*)(x  + (size_t)(m0 + row) * IN_DIM + kt + kq * 4);
      As[kq * 4 + 0][row] = a4.x;
      As[kq * 4 + 1][row] = a4.y;
      As[kq * 4 + 2][row] = a4.z;
      As[kq * 4 + 3][row] = a4.w;
      float4 b4 = *(const float4*)(We + (size_t)(n0 + row) * IN_DIM + kt + kq * 4);
      Bs[kq * 4 + 0][row] = b4.x;
      Bs[kq * 4 + 1][row] = b4.y;
      Bs[kq * 4 + 2][row] = b4.z;
      Bs[kq * 4 + 3][row] = b4.w;
    }
    __syncthreads();
#pragma unroll
    for (int kk = 0; kk < BKK; ++kk) {
      float4 a0 = *(const float4*)&As[kk][tm * 8];
      float4 a1 = *(const float4*)&As[kk][tm * 8 + 4];
      float4 b0 = *(const float4*)&Bs[kk][tn * 4];        // cols tn*4..+3
      float4 b1 = *(const float4*)&Bs[kk][tn * 4 + 64];   // cols 64+tn*4..+3
      float a[8] = {a0.x, a0.y, a0.z, a0.w, a1.x, a1.y, a1.z, a1.w};
      float b[8] = {b0.x, b0.y, b0.z, b0.w, b1.x, b1.y, b1.z, b1.w};
#pragma unroll
      for (int i = 0; i < 8; ++i)
#pragma unroll
        for (int j = 0; j < 8; ++j) acc[i][j] += a[i] * b[j];
    }
    __syncthreads();
  }

  float bev[8];
#pragma unroll
  for (int j = 0; j < 4; ++j) {
    bev[j]     = be[n0 + tn * 4 + j];
    bev[j + 4] = be[n0 + 64 + tn * 4 + j];
  }
#pragma unroll
  for (int i = 0; i < 8; ++i) {
    size_t base = (size_t)(m0 + tm * 8 + i) * LAT_DIM + n0;
    float4 c0 = make_float4(acc[i][0] + bev[0], acc[i][1] + bev[1],
                            acc[i][2] + bev[2], acc[i][3] + bev[3]);
    float4 c1 = make_float4(acc[i][4] + bev[4], acc[i][5] + bev[5],
                            acc[i][6] + bev[6], acc[i][7] + bev[7]);
    *(float4*)(lat + base + tn * 4)      = c0;
    *(float4*)(lat + base + 64 + tn * 4) = c1;
  }
}

// ================= Kernel 2: per-row top-32, sparsify in place, emit compact list =================
__global__ __launch_bounds__(256) void topk_kernel(
    const float* __restrict__ lat,   // dense latents [B][2560]
    float* __restrict__ sparse,      // same region, rewritten sparsified
    float* __restrict__ ws_val,      // [B][32]
    int*   __restrict__ ws_idx)      // [B][32]
{
  __shared__ float vrow_s[4][LAT_DIM];
  __shared__ float wval_s[4][KSEL];
  __shared__ int   widx_s[4][KSEL];

  const int wave = threadIdx.x >> 6;
  const int lane = threadIdx.x & 63;
  const size_t row = (size_t)blockIdx.x * 4 + wave;
  float* vrow = vrow_s[wave];
  const float* src = lat + row * LAT_DIM;

  const float NEG = -3.402823466e+38f;
  float gm[8];                // per-lane group maxes (groups of 5 of this lane's 40 elems)
  int   ge[8];
#pragma unroll
  for (int g = 0; g < 8; ++g) { gm[g] = NEG; ge[g] = 0; }

#pragma unroll
  for (int j = 0; j < 40; ++j) {
    int e = lane + 64 * j;    // this lane's elements, coalesced
    float v = src[e];
    vrow[e] = v;
    int g = j / 5;            // static per unrolled j
    if (v > gm[g]) { gm[g] = v; ge[g] = e; }
  }

  unsigned long long mask = 0ull;   // bit j: this lane's element j was selected

  for (int it = 0; it < KSEL; ++it) {
    // lane-local best among live groups (strict > keeps lowest index on ties)
    float cv = gm[0]; int ce = ge[0];
#pragma unroll
    for (int g = 1; g < 8; ++g)
      if (gm[g] > cv) { cv = gm[g]; ce = ge[g]; }
    // wave argmax, tie -> lower column index (matches jax.lax.top_k)
#pragma unroll
    for (int off = 32; off > 0; off >>= 1) {
      float ov = __shfl_xor(cv, off, 64);
      int   oe = __shfl_xor(ce, off, 64);
      if (ov > cv || (ov == cv && oe < ce)) { cv = ov; ce = oe; }
    }
    if (lane == 0) { wval_s[wave][it] = cv; widx_s[wave][it] = ce; }

    const int wl = ce & 63;   // owner lane
    const int jw = ce >> 6;   // owner's element slot 0..39
    if (wl == lane) mask |= 1ull << jw;
    // only the owner's affected group recomputes; static unroll avoids dynamic reg indexing
#pragma unroll
    for (int g = 0; g < 8; ++g) {
      if (wl == lane && (jw / 5) == g) {
        float m = NEG; int me = 0;
#pragma unroll
        for (int s = 0; s < 5; ++s) {
          int jj = g * 5 + s;
          float v = vrow[lane + 64 * jj];
          bool dead = (mask >> jj) & 1ull;
          if (!dead && v > m) { m = v; me = lane + 64 * jj; }
        }
        gm[g] = m; ge[g] = me;
      }
    }
  }

  __syncthreads();

  float* dst = sparse + row * LAT_DIM;
#pragma unroll
  for (int j = 0; j < 40; ++j) {
    int e = lane + 64 * j;
    float v = ((mask >> j) & 1ull) ? vrow[e] : 0.0f;
    dst[e] = v;
  }
  if (lane < KSEL) {
    ws_val[row * KSEL + lane] = wval_s[wave][lane];
    ws_idx[row * KSEL + lane] = widx_s[wave][lane];
  }
}

// ================= Kernel 3: sparse decode  recon = sparse @ Wd^T + bd =================
__global__ __launch_bounds__(256) void decoder_kernel(
    const float* __restrict__ ws_val,
    const int*   __restrict__ ws_idx,
    const unsigned short* __restrict__ WdT,  // bf16 [2560][640]
    const float* __restrict__ bd,            // [640]
    float* __restrict__ recon)               // [B][640]
{
  const int wave = threadIdx.x >> 6;
  const int lane = threadIdx.x & 63;
  const size_t row = (size_t)blockIdx.x * 4 + wave;

  float myv = 0.f; int myi = 0;
  if (lane < KSEL) {
    myv = ws_val[row * KSEL + lane];
    myi = ws_idx[row * KSEL + lane];
  }

  float2 acc[5];
#pragma unroll
  for (int u = 0; u < 5; ++u) {
    int i = 2 * lane + 128 * u;
    acc[u] = *(const float2*)(bd + i);
  }

#pragma unroll 4
  for (int j = 0; j < KSEL; ++j) {
    float vj = __shfl(myv, j, 64);
    int   ij = __shfl(myi, j, 64);
    const unsigned short* wr = WdT + (size_t)ij * IN_DIM;
#pragma unroll
    for (int u = 0; u < 5; ++u) {
      int i = 2 * lane + 128 * u;
      unsigned int w2 = *(const unsigned int*)(wr + i);   // two bf16, 4B aligned
      float w0 = __uint_as_float(w2 << 16);
      float w1 = __uint_as_float(w2 & 0xffff0000u);
      acc[u].x += vj * w0;
      acc[u].y += vj * w1;
    }
  }
#pragma unroll
  for (int u = 0; u < 5; ++u)
    *(float2*)(recon + row * IN_DIM + 2 * lane + 128 * u) = acc[u];
}

// ================= launch =================
extern "C" void kernel_launch(void* const* d_in, const int* in_sizes, int n_in,
                              void* d_out, int out_size, void* d_ws, size_t ws_size,
                              hipStream_t stream) {
  const float* x  = (const float*)d_in[0];
  const float* We = (const float*)d_in[1];
  const float* be = (const float*)d_in[2];
  const float* Wd = (const float*)d_in[3];
  const float* bd = (const float*)d_in[4];

  float* recon  = (float*)d_out;                               // [B*640]
  float* sparse = (float*)d_out + (size_t)BATCH * IN_DIM;      // [B*2560]

  float*          ws_val = (float*)d_ws;                                     // 8 MB
  int*            ws_idx = (int*)((char*)d_ws + (size_t)BATCH * KSEL * 4);   // 8 MB
  unsigned short* WdT    = (unsigned short*)((char*)d_ws + (size_t)BATCH * KSEL * 8);  // 3.27 MB

  transpose_wd <<<(LAT_DIM / 32) * (IN_DIM / 32), 256, 0, stream>>>(Wd, WdT);
  encoder_gemm <<<(BATCH / BM) * (LAT_DIM / BN),  256, 0, stream>>>(x, We, be, sparse);
  topk_kernel  <<<BATCH / 4, 256, 0, stream>>>(sparse, sparse, ws_val, ws_idx);
  decoder_kernel<<<BATCH / 4, 256, 0, stream>>>(ws_val, ws_idx, WdT, bd, recon);
}

// Round 2
// 2430.047 us; speedup vs baseline: 1.6717x; 1.6717x over previous
//
#include <hip/hip_runtime.h>
#include <cstdint>

#define BATCH   65536
#define IN_DIM  640
#define LAT_DIM 2560
#define KSEL    32

typedef short  v8s __attribute__((ext_vector_type(8)));
typedef float  v4f __attribute__((ext_vector_type(4)));

__device__ inline void async_load16(void* lds, const void* g) {
  __builtin_amdgcn_global_load_lds(
      (const __attribute__((address_space(1))) unsigned int*)g,
      (__attribute__((address_space(3))) unsigned int*)lds, 16, 0, 0);
}

__device__ inline unsigned short f2bf(float v) {
  unsigned int b = __float_as_uint(v);
  return (unsigned short)((b + 0x7fffu + ((b >> 16) & 1u)) >> 16);
}

// ============ conv fp32 -> bf16, 8 elems/thread ============
__global__ __launch_bounds__(256) void conv_bf16(
    const float* __restrict__ src, unsigned short* __restrict__ dst, int n8)
{
  int i = blockIdx.x * 256 + threadIdx.x;
  if (i >= n8) return;
  const float4* s4 = (const float4*)(src) + i * 2;
  float4 a = s4[0], b = s4[1];
  ushort4 lo = make_ushort4(f2bf(a.x), f2bf(a.y), f2bf(a.z), f2bf(a.w));
  ushort4 hi = make_ushort4(f2bf(b.x), f2bf(b.y), f2bf(b.z), f2bf(b.w));
  *(ushort4*)(dst + (size_t)i * 8)     = lo;
  *(ushort4*)(dst + (size_t)i * 8 + 4) = hi;
}

// ============ transpose Wd [640][2560] -> WdT bf16 [2560][640] ============
__global__ __launch_bounds__(256) void transpose_wd(
    const float* __restrict__ Wd, unsigned short* __restrict__ WdT)
{
  __shared__ float tile[32][33];
  const int tx = threadIdx.x & 31;
  const int ty = threadIdx.x >> 5;
  const int l0 = (blockIdx.x % (LAT_DIM / 32)) * 32;
  const int i0 = (blockIdx.x / (LAT_DIM / 32)) * 32;
#pragma unroll
  for (int s = 0; s < 4; ++s)
    tile[ty + 8 * s][tx] = Wd[(size_t)(i0 + ty + 8 * s) * LAT_DIM + l0 + tx];
  __syncthreads();
#pragma unroll
  for (int s = 0; s < 4; ++s)
    WdT[(size_t)(l0 + ty + 8 * s) * IN_DIM + i0 + tx] = f2bf(tile[tx][ty + 8 * s]);
}

// ============ encoder: lat = x @ We^T + be, bf16 MFMA, fp32 out ============
// 128x128 tile, BK=32, 4 waves each 64x64, 16x16x32 MFMA (m97 structure).
__global__ __launch_bounds__(256) void encoder_mfma(
    const unsigned short* __restrict__ xb,   // bf16 [B][640]
    const unsigned short* __restrict__ web,  // bf16 [2560][640]
    const float* __restrict__ be,
    float* __restrict__ lat)                 // fp32 [B][2560]
{
  __shared__ unsigned short As[128 * 32];
  __shared__ unsigned short Bs[128 * 32];

  const int t = threadIdx.x, lane = t & 63, wave = t >> 6;
  const int nt = blockIdx.x % (LAT_DIM / 128);
  const int mt = blockIdx.x / (LAT_DIM / 128);
  const int m0 = mt * 128, n0 = nt * 128;
  const int mBase = (wave & 1) * 64, nBase = (wave >> 1) * 64;

  v4f acc[4][4];
#pragma unroll
  for (int mi = 0; mi < 4; ++mi)
#pragma unroll
    for (int ni = 0; ni < 4; ++ni) acc[mi][ni] = (v4f){0.f, 0.f, 0.f, 0.f};

  const int s1 = t, s2 = t + 256;
  const int r1 = s1 >> 2, q1 = s1 & 3, r2 = s2 >> 2, q2 = s2 & 3;
  const unsigned short* gA1 = xb  + (size_t)(m0 + r1) * IN_DIM + q1 * 8;
  const unsigned short* gA2 = xb  + (size_t)(m0 + r2) * IN_DIM + q2 * 8;
  const unsigned short* gB1 = web + (size_t)(n0 + r1) * IN_DIM + q1 * 8;
  const unsigned short* gB2 = web + (size_t)(n0 + r2) * IN_DIM + q2 * 8;
  unsigned short* lA1 = As + s1 * 8;  unsigned short* lA2 = As + s2 * 8;
  unsigned short* lB1 = Bs + s1 * 8;  unsigned short* lB2 = Bs + s2 * 8;

  const int arow = (mBase + (lane & 15)) * 32 + (lane >> 4) * 8;
  const int brow = (nBase + (lane & 15)) * 32 + (lane >> 4) * 8;

  for (int kt = 0; kt < IN_DIM; kt += 32) {
    async_load16(lA1, gA1 + kt);
    async_load16(lA2, gA2 + kt);
    async_load16(lB1, gB1 + kt);
    async_load16(lB2, gB2 + kt);
    __syncthreads();
    v8s a[4], b[4];
#pragma unroll
    for (int mi = 0; mi < 4; ++mi) a[mi] = *(const v8s*)(As + arow + mi * 16 * 32);
#pragma unroll
    for (int ni = 0; ni < 4; ++ni) b[ni] = *(const v8s*)(Bs + brow + ni * 16 * 32);
#pragma unroll
    for (int mi = 0; mi < 4; ++mi)
#pragma unroll
      for (int ni = 0; ni < 4; ++ni)
        acc[mi][ni] = __builtin_amdgcn_mfma_f32_16x16x32_bf16(a[mi], b[ni], acc[mi][ni], 0, 0, 0);
    __syncthreads();
  }

  float bev[4];
#pragma unroll
  for (int ni = 0; ni < 4; ++ni) bev[ni] = be[n0 + nBase + ni * 16 + (lane & 15)];
#pragma unroll
  for (int mi = 0; mi < 4; ++mi) {
    const int grow0 = m0 + mBase + mi * 16 + (lane >> 4) * 4;
#pragma unroll
    for (int ni = 0; ni < 4; ++ni) {
      const int gcol = n0 + nBase + ni * 16 + (lane & 15);
#pragma unroll
      for (int r = 0; r < 4; ++r)
        lat[(size_t)(grow0 + r) * LAT_DIM + gcol] = acc[mi][ni][r] + bev[ni];
    }
  }
}

// ============ topk: candidates by threshold, exact recompute in +/-W window ============
#define TK_CAP 160
#define TK_WIN 0.012f

__global__ __launch_bounds__(256) void topk2(
    float* __restrict__ lat,            // dense noisy in, sparse out (in place)
    const float* __restrict__ x,        // fp32 [B][640]
    const float* __restrict__ We,       // fp32 [2560][640]
    const float* __restrict__ be,
    float* __restrict__ ws_val, int* __restrict__ ws_idx)
{
  __shared__ float cval[4][TK_CAP];
  __shared__ int   cidx[4][TK_CAP];
  __shared__ unsigned char elig[4][TK_CAP];
  __shared__ int   winl[4][48];
  __shared__ int   seli[4][KSEL];
  __shared__ float v32s[4];

  const int wave = threadIdx.x >> 6, lane = threadIdx.x & 63;
  const size_t row = (size_t)blockIdx.x * 4 + wave;
  float* rowp = lat + row * LAT_DIM;
  const unsigned long long lmask = (1ull << lane) - 1ull;

  float v[40];
#pragma unroll
  for (int j = 0; j < 40; ++j) v[j] = rowp[lane + 64 * j];

  // row RMS -> initial threshold at ~rank-64 quantile
  float ss = 0.f;
#pragma unroll
  for (int j = 0; j < 40; ++j) ss = fmaf(v[j], v[j], ss);
#pragma unroll
  for (int off = 32; off > 0; off >>= 1) ss += __shfl_xor(ss, off, 64);
  const float sigma = sqrtf(ss * (1.0f / LAT_DIM));
  float T = 1.96f * sigma;

  int cnt = 0;
  for (int it = 0; it < 40; ++it) {
    cnt = 0;
#pragma unroll
    for (int j = 0; j < 40; ++j) cnt += (int)__popcll(__ballot(v[j] > T));
    if (cnt >= 44 && cnt <= TK_CAP) break;
    T += (cnt < 44) ? (-0.25f * sigma) : (0.10f * sigma);
  }

  // collect candidates (val, idx) via ballot compaction
  int base = 0;
#pragma unroll
  for (int j = 0; j < 40; ++j) {
    unsigned long long b = __ballot(v[j] > T);
    if (v[j] > T) {
      int p = base + (int)__popcll(b & lmask);
      if (p < TK_CAP) { cval[wave][p] = v[j]; cidx[wave][p] = lane + 64 * j; }
    }
    base += (int)__popcll(b);
  }
  cnt = base < TK_CAP ? base : TK_CAP;

  // rank pass 1 (noisy) -> find v32 (rank 31, tie -> lower index)
  for (int r = 0; r < 3; ++r) {
    int e = lane + 64 * r;
    if (e < cnt) {
      float ev = cval[wave][e]; int ei = cidx[wave][e];
      int rk = 0;
      for (int f = 0; f < cnt; ++f) {
        float fv = cval[wave][f];
        rk += (fv > ev) || (fv == ev && cidx[wave][f] < ei);
      }
      if (rk == 31) v32s[wave] = ev;
    }
  }
  const float v32 = v32s[wave];

  // eligibility + window list
  int wbase = 0;
#pragma unroll
  for (int r = 0; r < 3; ++r) {
    int e = lane + 64 * r;
    bool in = (e < cnt);
    float ev = in ? cval[wave][e] : -1e30f;
    if (in) elig[wave][e] = (ev >= v32 - TK_WIN) ? 1 : 0;
    bool wn = in && (fabsf(ev - v32) <= TK_WIN);
    unsigned long long b = __ballot(wn);
    if (wn) {
      int p = wbase + (int)__popcll(b & lmask);
      if (p < 48) winl[wave][p] = e;
    }
    wbase += (int)__popcll(b);
  }
  const int wcnt = wbase < 48 ? wbase : 48;

  // exact recompute: strictly-sequential ascending-k fp32 fma chain (matches np/BLAS order)
  if (lane < wcnt) {
    int slot = winl[wave][lane];
    int c = cidx[wave][slot];
    const float4* x4 = (const float4*)(x + row * IN_DIM);
    const float4* w4 = (const float4*)(We + (size_t)c * IN_DIM);
    float acc = 0.f;
#pragma unroll 4
    for (int i = 0; i < IN_DIM / 4; ++i) {
      float4 xv = x4[i], wv = w4[i];
      acc = fmaf(xv.x, wv.x, acc);
      acc = fmaf(xv.y, wv.y, acc);
      acc = fmaf(xv.z, wv.z, acc);
      acc = fmaf(xv.w, wv.w, acc);
    }
    cval[wave][slot] = acc + be[c];
  }

  // rank pass 2 among eligible with substituted exact values -> final 32
  for (int r = 0; r < 3; ++r) {
    int e = lane + 64 * r;
    if (e < cnt && elig[wave][e]) {
      float ev = cval[wave][e]; int ei = cidx[wave][e];
      int rk = 0;
      for (int f = 0; f < cnt; ++f) {
        if (!elig[wave][f]) continue;
        float fv = cval[wave][f];
        rk += (fv > ev) || (fv == ev && cidx[wave][f] < ei);
      }
      if (rk < KSEL) {
        ws_val[row * KSEL + rk] = ev;
        ws_idx[row * KSEL + rk] = ei;
        seli[wave][rk] = ei;
      }
    }
  }

  // build per-lane selection mask, write sparse row (noisy values)
  unsigned long long m = 0ull;
#pragma unroll
  for (int s = 0; s < KSEL; ++s) {
    int idx = seli[wave][s];
    if ((idx & 63) == lane) m |= 1ull << (idx >> 6);
  }
#pragma unroll
  for (int j = 0; j < 40; ++j)
    rowp[lane + 64 * j] = ((m >> j) & 1ull) ? v[j] : 0.f;
}

// ============ decoder: recon = sparse @ Wd^T + bd (bf16 WdT gather) ============
__global__ __launch_bounds__(256) void decoder_kernel(
    const float* __restrict__ ws_val,
    const int*   __restrict__ ws_idx,
    const unsigned short* __restrict__ WdT,
    const float* __restrict__ bd,
    float* __restrict__ recon)
{
  const int wave = threadIdx.x >> 6, lane = threadIdx.x & 63;
  const size_t row = (size_t)blockIdx.x * 4 + wave;

  float myv = 0.f; int myi = 0;
  if (lane < KSEL) { myv = ws_val[row * KSEL + lane]; myi = ws_idx[row * KSEL + lane]; }

  float2 acc[5];
#pragma unroll
  for (int u = 0; u < 5; ++u) acc[u] = *(const float2*)(bd + 2 * lane + 128 * u);

#pragma unroll 4
  for (int j = 0; j < KSEL; ++j) {
    float vj = __shfl(myv, j, 64);
    int   ij = __shfl(myi, j, 64);
    const unsigned short* wr = WdT + (size_t)ij * IN_DIM;
#pragma unroll
    for (int u = 0; u < 5; ++u) {
      unsigned int w2 = *(const unsigned int*)(wr + 2 * lane + 128 * u);
      acc[u].x += vj * __uint_as_float(w2 << 16);
      acc[u].y += vj * __uint_as_float(w2 & 0xffff0000u);
    }
  }
#pragma unroll
  for (int u = 0; u < 5; ++u)
    *(float2*)(recon + row * IN_DIM + 2 * lane + 128 * u) = acc[u];
}

// ============ launch ============
extern "C" void kernel_launch(void* const* d_in, const int* in_sizes, int n_in,
                              void* d_out, int out_size, void* d_ws, size_t ws_size,
                              hipStream_t stream) {
  const float* x  = (const float*)d_in[0];
  const float* We = (const float*)d_in[1];
  const float* be = (const float*)d_in[2];
  const float* Wd = (const float*)d_in[3];
  const float* bd = (const float*)d_in[4];

  float* recon  = (float*)d_out;
  float* sparse = (float*)d_out + (size_t)BATCH * IN_DIM;   // also dense-latent scratch

  char* ws = (char*)d_ws;
  float*          ws_val = (float*)ws;                                   ws += (size_t)BATCH * KSEL * 4;
  int*            ws_idx = (int*)ws;                                     ws += (size_t)BATCH * KSEL * 4;
  unsigned short* WdT    = (unsigned short*)ws;                          ws += (size_t)LAT_DIM * IN_DIM * 2;
  unsigned short* x_bf   = (unsigned short*)ws;                          ws += (size_t)BATCH * IN_DIM * 2;
  unsigned short* We_bf  = (unsigned short*)ws;

  conv_bf16    <<<(BATCH * IN_DIM / 8 + 255) / 256, 256, 0, stream>>>(x, x_bf, BATCH * IN_DIM / 8);
  conv_bf16    <<<(LAT_DIM * IN_DIM / 8 + 255) / 256, 256, 0, stream>>>(We, We_bf, LAT_DIM * IN_DIM / 8);
  transpose_wd <<<(LAT_DIM / 32) * (IN_DIM / 32), 256, 0, stream>>>(Wd, WdT);
  encoder_mfma <<<(BATCH / 128) * (LAT_DIM / 128), 256, 0, stream>>>(x_bf, We_bf, be, sparse);
  topk2        <<<BATCH / 4, 256, 0, stream>>>(sparse, x, We, be, ws_val, ws_idx);
  decoder_kernel<<<BATCH / 4, 256, 0, stream>>>(ws_val, ws_idx, WdT, bd, recon);
}